// Round 2
// 404.347 us; speedup vs baseline: 1.2630x; 1.2630x over previous
//
#include <hip/hip_runtime.h>
#include <cmath>

// DarwinianRouter r6 (= r5 resubmit; r5 bench died to container infra failure,
// audit found no fault path — see journal).
// r4 diagnosis: gemm at 214us with MfmaUtil 9.5%/VALUBusy 13%/HBM 13% =
// latency-tail-bound (scattered 32B x 8KB-stride B loads, 32 L2 transactions
// per frag load), plus ~290us hidden in P-materialization + serial reduce_topk.
// r5/r6: (1) block = 32 tokens x 8 waves, each wave K-chunk of 512, LDS 2-stage
// reduce -> write final normalized resonance directly (P/SS eliminated);
// (2) B planes repacked [tile][kb][lane][8] so every B-frag load is a
// contiguous 1KB wave transaction; (3) A prefetch distance 2 to stream x at
// HBM rate. Top-8 via wave-per-token 64-bit-key shfl reduction.

#define N_TOKENS 16384
#define DIM      4096
#define NE       64
#define TOPK     8
#define SCALE    5.0f
#define EPS      1e-12f
#define NS       32        // K-steps per wave (512/16)

typedef short  frag   __attribute__((ext_vector_type(8)));   // 8 bf16 bit-patterns
typedef float  f32x16 __attribute__((ext_vector_type(16)));  // 32x32 C/D
typedef int    i32x4  __attribute__((ext_vector_type(4)));
typedef short  short4v __attribute__((ext_vector_type(4)));

__device__ __forceinline__ void split3(float v, unsigned& h1, unsigned& h2, unsigned& h3) {
    unsigned u  = __builtin_bit_cast(unsigned, v);
    unsigned r1 = (u + 0x7FFFu + ((u >> 16) & 1u)) & 0xFFFF0000u;
    float    d1 = v - __builtin_bit_cast(float, r1);
    unsigned w  = __builtin_bit_cast(unsigned, d1);
    unsigned r2 = (w + 0x7FFFu + ((w >> 16) & 1u)) & 0xFFFF0000u;
    float    d2 = d1 - __builtin_bit_cast(float, r2);
    unsigned z  = __builtin_bit_cast(unsigned, d2);
    unsigned r3 = (z + 0x7FFFu + ((z >> 16) & 1u)) & 0xFFFF0000u;
    h1 = r1 >> 16; h2 = r2 >> 16; h3 = r3 >> 16;
}

// sig split + repack into MFMA-frag-coalesced layout:
// plane[tile(2)][kb(256)][lane(64)][8], lane = half*32 + (e&31),
// element (lane,i) = sig_split[e = tile*32 + (lane&31)][k = kb*16 + half*8 + i].
__launch_bounds__(256)
__global__ void convert_sig(const float* __restrict__ sig,
                            short* __restrict__ h1,
                            short* __restrict__ h2,
                            short* __restrict__ h3) {
    const int tid = blockIdx.x * 256 + threadIdx.x;   // 65536 threads, 4 elems each
    const int e   = tid >> 10;                        // 1024 threads per expert
    const int kq  = (tid & 1023) << 2;
    const float4 v = *(const float4*)(sig + (size_t)e * DIM + kq);
    const float vs[4] = {v.x, v.y, v.z, v.w};
    const int tile = e >> 5, e31 = e & 31;
    const int kb = kq >> 4, hf = (kq >> 3) & 1, off = kq & 7;
    const int lane = (hf << 5) | e31;
    const int base = ((tile * 256 + kb) * 64 + lane) * 8 + off;
    short4v o1, o2, o3;
#pragma unroll
    for (int p = 0; p < 4; ++p) {
        unsigned a, b, c;
        split3(vs[p], a, b, c);
        o1[p] = (short)a; o2[p] = (short)b; o3[p] = (short)c;
    }
    *(short4v*)(h1 + base) = o1;
    *(short4v*)(h2 + base) = o2;
    *(short4v*)(h3 + base) = o3;
}

// grid N_TOKENS/32 blocks x 512 threads (8 waves). Block owns 32 tokens,
// full K=4096. Wave w: K-chunk [w*512,(w+1)*512), 32 steps, all 64 experts
// (two 32x32 tiles), 3-way bf16 split, 6 MFMA products per tile per step.
// Epilogue: LDS 2-stage cross-wave reduce + L2-norm scale -> outR.
__launch_bounds__(512, 4)
__global__ void gemm_fused(const float* __restrict__ x,
                           const short* __restrict__ sh1,
                           const short* __restrict__ sh2,
                           const short* __restrict__ sh3,
                           float* __restrict__ outR) {
    __shared__ float red[4][64][34];   // stride 34: 8B-aligned, 2-way-bank free
    __shared__ float sqred[8][32];
    __shared__ float scl[32];

    const int t    = threadIdx.x;
    const int lane = t & 63;
    const int w    = t >> 6;
    const int l31  = lane & 31;
    const int half = lane >> 5;

    const int tb = blockIdx.x * 32;
    const int k0 = w * (DIM / 8);                 // 512 per wave

    // A: lane = token row l31, k = k0 + 16*st + 8*half + [0..7]
    const float* ap = x + (size_t)(tb + l31) * DIM + k0 + 8 * half;
    // B: packed layout, per-step stride = 64*8 shorts = 1KB contiguous per wave
    const int bbase = ((w * NS) * 64 + lane) * 8;
    const short* b1p = sh1 + bbase;
    const short* b2p = sh2 + bbase;
    const short* b3p = sh3 + bbase;
    const int TILE1 = 256 * 64 * 8;               // +tile1 (experts 32..63)

    f32x16 c0 = {};   // experts 0..31
    f32x16 c1 = {};   // experts 32..63
    float sq = 0.f;

    // A prefetch pipeline, distance 2
    float4 cur0 = *(const float4*)(ap);
    float4 cur1 = *(const float4*)(ap + 4);
    float4 nxt0 = *(const float4*)(ap + 16);
    float4 nxt1 = *(const float4*)(ap + 20);

#pragma unroll 2
    for (int st = 0; st < NS; ++st) {
        const frag b1a = *(const frag*)(b1p);
        const frag b1b = *(const frag*)(b1p + TILE1);
        const frag b2a = *(const frag*)(b2p);
        const frag b2b = *(const frag*)(b2p + TILE1);
        const frag b3a = *(const frag*)(b3p);
        const frag b3b = *(const frag*)(b3p + TILE1);

        float4 f0 = cur0, f1 = cur1;
        if (st + 2 < NS) {
            f0 = *(const float4*)(ap + 32);
            f1 = *(const float4*)(ap + 36);
        }

        const float vals[8] = {cur0.x, cur0.y, cur0.z, cur0.w,
                               cur1.x, cur1.y, cur1.z, cur1.w};
        i32x4 a1i, a2i, a3i;
#pragma unroll
        for (int p = 0; p < 4; ++p) {
            const float v0 = vals[2 * p], v1 = vals[2 * p + 1];
            sq = fmaf(v0, v0, sq);
            sq = fmaf(v1, v1, sq);
            unsigned h10, h20, h30, h11, h21, h31;
            split3(v0, h10, h20, h30);
            split3(v1, h11, h21, h31);
            a1i[p] = (int)(h10 | (h11 << 16));
            a2i[p] = (int)(h20 | (h21 << 16));
            a3i[p] = (int)(h30 | (h31 << 16));
        }
        const frag A1 = __builtin_bit_cast(frag, a1i);
        const frag A2 = __builtin_bit_cast(frag, a2i);
        const frag A3 = __builtin_bit_cast(frag, a3i);

        // 6 products/tile: h1h1 + (h1h2+h2h1) + (h1h3+h3h1+h2h2), c0/c1 interleaved
        c0 = __builtin_amdgcn_mfma_f32_32x32x16_bf16(A1, b1a, c0, 0, 0, 0);
        c1 = __builtin_amdgcn_mfma_f32_32x32x16_bf16(A1, b1b, c1, 0, 0, 0);
        c0 = __builtin_amdgcn_mfma_f32_32x32x16_bf16(A1, b2a, c0, 0, 0, 0);
        c1 = __builtin_amdgcn_mfma_f32_32x32x16_bf16(A1, b2b, c1, 0, 0, 0);
        c0 = __builtin_amdgcn_mfma_f32_32x32x16_bf16(A2, b1a, c0, 0, 0, 0);
        c1 = __builtin_amdgcn_mfma_f32_32x32x16_bf16(A2, b1b, c1, 0, 0, 0);
        c0 = __builtin_amdgcn_mfma_f32_32x32x16_bf16(A1, b3a, c0, 0, 0, 0);
        c1 = __builtin_amdgcn_mfma_f32_32x32x16_bf16(A1, b3b, c1, 0, 0, 0);
        c0 = __builtin_amdgcn_mfma_f32_32x32x16_bf16(A3, b1a, c0, 0, 0, 0);
        c1 = __builtin_amdgcn_mfma_f32_32x32x16_bf16(A3, b1b, c1, 0, 0, 0);
        c0 = __builtin_amdgcn_mfma_f32_32x32x16_bf16(A2, b2a, c0, 0, 0, 0);
        c1 = __builtin_amdgcn_mfma_f32_32x32x16_bf16(A2, b2b, c1, 0, 0, 0);

        cur0 = nxt0; cur1 = nxt1; nxt0 = f0; nxt1 = f1;
        ap += 16; b1p += 512; b2p += 512; b3p += 512;
    }

    // per-token sumsq for this wave's K-chunk (lanes l and l+32 share a token)
    sq += __shfl_xor(sq, 32);
    if (lane < 32) sqred[w][l31] = sq;

    // stage 1: waves 4..7 deposit
    if (w >= 4) {
#pragma unroll
        for (int r = 0; r < 16; ++r) {
            red[w - 4][lane][r]      = c0[r];
            red[w - 4][lane][16 + r] = c1[r];
        }
    }
    __syncthreads();

    // L2-norm scale per token (full K)
    if (t < 32) {
        float q = 0.f;
#pragma unroll
        for (int ww = 0; ww < 8; ++ww) q += sqred[ww][t];
        scl[t] = SCALE / fmaxf(sqrtf(q), EPS);
    }

    // stage 2: waves 0..3 fold in their registers (thread-private cells)
    if (w < 4) {
#pragma unroll
        for (int r = 0; r < 16; ++r) {
            const float s0 = c0[r] + red[w][lane][r];
            const float s1 = c1[r] + red[w][lane][16 + r];
            red[w][lane][r]      = s0;
            red[w][lane][16 + r] = s1;
        }
    }
    __syncthreads();

    // gather: wave w owns regs R = 4w..4w+3; token=(R&3)+8*((R&15)>>2)+4*half,
    // expert = l31 + 32*(R>>4)  (verified 32x32 C/D mapping from r4 epilogue)
    const int wm = w & 3, tile = w >> 2;
    const int et = l31 + 32 * tile;
#pragma unroll
    for (int j = 0; j < 4; ++j) {
        const int R = 4 * w + j;
        const float a = red[0][lane][R] + red[1][lane][R] +
                        red[2][lane][R] + red[3][lane][R];
        const int token = j + 8 * wm + 4 * half;
        outR[(size_t)(tb + token) * NE + et] = a * scl[token];
    }
}

// wave-per-token top-8: 64-bit key = sortable(f32)<<32 | (63-e) so max-reduce
// picks highest value, ties -> lowest expert index (= jax.lax.top_k order).
__launch_bounds__(256)
__global__ void topk_wave(const float* __restrict__ outR,
                          float* __restrict__ outW,
                          float* __restrict__ outI) {
    const int t    = threadIdx.x;
    const int lane = t & 63;
    const int w    = t >> 6;
    const int tok  = blockIdx.x * 4 + w;

    const float v = outR[(size_t)tok * NE + lane];
    const unsigned u = __builtin_bit_cast(unsigned, v);
    const unsigned s = u ^ ((unsigned)(((int)u) >> 31) | 0x80000000u);
    unsigned long long cur = ((unsigned long long)s << 32) | (unsigned)(63 - lane);

    float bw = 0.f;
    int   bi = 0;
#pragma unroll
    for (int m = 0; m < TOPK; ++m) {
        unsigned long long r = cur;
#pragma unroll
        for (int d = 32; d >= 1; d >>= 1) {
            const unsigned long long o = __shfl_xor(r, d);
            r = (o > r) ? o : r;
        }
        const int we = 63 - (int)(r & 63ull);   // uniform across wave
        const float bv = __shfl(v, we);
        if (lane == we) cur = 0ull;             // remove winner
        if (lane == m) { bw = bv; bi = we; }
    }
    if (lane < TOPK) {
        outW[(size_t)tok * TOPK + lane] = log1pf(expf(bw));
        outI[(size_t)tok * TOPK + lane] = (float)bi;
    }
}

extern "C" void kernel_launch(void* const* d_in, const int* in_sizes, int n_in,
                              void* d_out, int out_size, void* d_ws, size_t ws_size,
                              hipStream_t stream) {
    const float* x   = (const float*)d_in[0];
    const float* sig = (const float*)d_in[1];
    float* out  = (float*)d_out;
    float* outW = out;
    float* outI = out + (size_t)N_TOKENS * TOPK;
    float* outR = out + (size_t)N_TOKENS * TOPK * 2;

    const size_t SIGE = (size_t)NE * DIM;   // 262144 elems per plane
    short* sh1 = (short*)d_ws;              // 3 planes = 1.5 MB total
    short* sh2 = sh1 + SIGE;
    short* sh3 = sh2 + SIGE;

    convert_sig<<<256, 256, 0, stream>>>(sig, sh1, sh2, sh3);
    gemm_fused<<<N_TOKENS / 32, 512, 0, stream>>>(x, sh1, sh2, sh3, outR);
    topk_wave<<<N_TOKENS / 4, 256, 0, stream>>>(outR, outW, outI);
}

// Round 3
// 396.611 us; speedup vs baseline: 1.2877x; 1.0195x over previous
//
#include <hip/hip_runtime.h>
#include <cmath>

// DarwinianRouter r7.
// r6 result: 404us total; top-5 all 1GiB fillBuffer (ws poison, ~161us, likely
// inside the timed window); our kernels all <163us => no direct counters.
// Model: 404 = 161 fill + ~150 gemm + ~80 (convert+topk+gaps).
// r7: (1) top-8 fused into gemm epilogue (res already in LDS; per-wave 64-bit
// key shfl top-8, 4 tokens/wave) -> topk_wave kernel deleted; (2) convert_sig
// rewritten with coalesced 16B frag stores; (3) gemm unroll 1 for VGPR safety
// (128-reg cap at launch_bounds(512,4), 32 regs are unified-file accumulators).

#define N_TOKENS 16384
#define DIM      4096
#define NE       64
#define TOPK     8
#define SCALE    5.0f
#define EPS      1e-12f
#define NS       32        // K-steps per wave (512/16)

typedef short  frag   __attribute__((ext_vector_type(8)));   // 8 bf16 bit-patterns
typedef float  f32x16 __attribute__((ext_vector_type(16)));  // 32x32 C/D
typedef int    i32x4  __attribute__((ext_vector_type(4)));

__device__ __forceinline__ void split3(float v, unsigned& h1, unsigned& h2, unsigned& h3) {
    unsigned u  = __builtin_bit_cast(unsigned, v);
    unsigned r1 = (u + 0x7FFFu + ((u >> 16) & 1u)) & 0xFFFF0000u;
    float    d1 = v - __builtin_bit_cast(float, r1);
    unsigned w  = __builtin_bit_cast(unsigned, d1);
    unsigned r2 = (w + 0x7FFFu + ((w >> 16) & 1u)) & 0xFFFF0000u;
    float    d2 = d1 - __builtin_bit_cast(float, r2);
    unsigned z  = __builtin_bit_cast(unsigned, d2);
    unsigned r3 = (z + 0x7FFFu + ((z >> 16) & 1u)) & 0xFFFF0000u;
    h1 = r1 >> 16; h2 = r2 >> 16; h3 = r3 >> 16;
}

// sig split + repack, frag-coalesced layout: plane[tile(2)][kb(256)][lane(64)][8],
// lane = (hf<<5)|e31; element (lane,i) = split(sig[e=tile*32+e31][k=kb*16+hf*8+i]).
// One thread = one full frag per plane => contiguous 1KB wave stores.
__launch_bounds__(256)
__global__ void convert_sig(const float* __restrict__ sig,
                            short* __restrict__ h1,
                            short* __restrict__ h2,
                            short* __restrict__ h3) {
    const int tid  = blockIdx.x * 256 + threadIdx.x;   // 32768 threads (128 blocks)
    const int lane = tid & 63;
    const int kb   = (tid >> 6) & 255;
    const int tile = tid >> 14;
    const int e31  = lane & 31, hf = lane >> 5;
    const float* src = sig + (size_t)(tile * 32 + e31) * DIM + kb * 16 + hf * 8;
    const float4 v0 = *(const float4*)(src);
    const float4 v1 = *(const float4*)(src + 4);
    const float vs[8] = {v0.x, v0.y, v0.z, v0.w, v1.x, v1.y, v1.z, v1.w};
    frag o1, o2, o3;
#pragma unroll
    for (int p = 0; p < 8; ++p) {
        unsigned a, b, c;
        split3(vs[p], a, b, c);
        o1[p] = (short)a; o2[p] = (short)b; o3[p] = (short)c;
    }
    const int base = ((tile * 256 + kb) * 64 + lane) * 8;
    *(frag*)(h1 + base) = o1;
    *(frag*)(h2 + base) = o2;
    *(frag*)(h3 + base) = o3;
}

// grid N_TOKENS/32 blocks x 512 threads (8 waves). Block owns 32 tokens,
// full K=4096. Wave w: K-chunk [w*512,(w+1)*512), 32 steps, all 64 experts
// (two 32x32 tiles), 3-way bf16 split, 6 MFMA products per tile per step.
// Epilogue: LDS 2-stage cross-wave reduce + L2-norm scale -> outR + fused top-8.
__launch_bounds__(512, 4)
__global__ void gemm_fused(const float* __restrict__ x,
                           const short* __restrict__ sh1,
                           const short* __restrict__ sh2,
                           const short* __restrict__ sh3,
                           float* __restrict__ outR,
                           float* __restrict__ outW,
                           float* __restrict__ outI) {
    __shared__ float red[4][64][34];   // cross-wave partial sums
    __shared__ float res[32][68];      // final scaled resonance [token][expert]
    __shared__ float sqred[8][32];
    __shared__ float scl[32];

    const int t    = threadIdx.x;
    const int lane = t & 63;
    const int w    = t >> 6;
    const int l31  = lane & 31;
    const int half = lane >> 5;

    const int tb = blockIdx.x * 32;
    const int k0 = w * (DIM / 8);                 // 512 per wave

    // A: lane = token row l31, k = k0 + 16*st + 8*half + [0..7]
    const float* ap = x + (size_t)(tb + l31) * DIM + k0 + 8 * half;
    // B: packed layout, per-step stride = 64*8 shorts = 1KB contiguous per wave
    const int bbase = ((w * NS) * 64 + lane) * 8;
    const short* b1p = sh1 + bbase;
    const short* b2p = sh2 + bbase;
    const short* b3p = sh3 + bbase;
    const int TILE1 = 256 * 64 * 8;               // +tile1 (experts 32..63)

    f32x16 c0 = {};   // experts 0..31
    f32x16 c1 = {};   // experts 32..63
    float sq = 0.f;

    // A prefetch pipeline, distance 2
    float4 cur0 = *(const float4*)(ap);
    float4 cur1 = *(const float4*)(ap + 4);
    float4 nxt0 = *(const float4*)(ap + 16);
    float4 nxt1 = *(const float4*)(ap + 20);

#pragma unroll 1
    for (int st = 0; st < NS; ++st) {
        const frag b1a = *(const frag*)(b1p);
        const frag b1b = *(const frag*)(b1p + TILE1);
        const frag b2a = *(const frag*)(b2p);
        const frag b2b = *(const frag*)(b2p + TILE1);
        const frag b3a = *(const frag*)(b3p);
        const frag b3b = *(const frag*)(b3p + TILE1);

        float4 f0 = cur0, f1 = cur1;
        if (st + 2 < NS) {
            f0 = *(const float4*)(ap + 32);
            f1 = *(const float4*)(ap + 36);
        }

        const float vals[8] = {cur0.x, cur0.y, cur0.z, cur0.w,
                               cur1.x, cur1.y, cur1.z, cur1.w};
        i32x4 a1i, a2i, a3i;
#pragma unroll
        for (int p = 0; p < 4; ++p) {
            const float v0 = vals[2 * p], v1 = vals[2 * p + 1];
            sq = fmaf(v0, v0, sq);
            sq = fmaf(v1, v1, sq);
            unsigned h10, h20, h30, h11, h21, h31;
            split3(v0, h10, h20, h30);
            split3(v1, h11, h21, h31);
            a1i[p] = (int)(h10 | (h11 << 16));
            a2i[p] = (int)(h20 | (h21 << 16));
            a3i[p] = (int)(h30 | (h31 << 16));
        }
        const frag A1 = __builtin_bit_cast(frag, a1i);
        const frag A2 = __builtin_bit_cast(frag, a2i);
        const frag A3 = __builtin_bit_cast(frag, a3i);

        // 6 products/tile: h1h1 + (h1h2+h2h1) + (h1h3+h3h1+h2h2), c0/c1 interleaved
        c0 = __builtin_amdgcn_mfma_f32_32x32x16_bf16(A1, b1a, c0, 0, 0, 0);
        c1 = __builtin_amdgcn_mfma_f32_32x32x16_bf16(A1, b1b, c1, 0, 0, 0);
        c0 = __builtin_amdgcn_mfma_f32_32x32x16_bf16(A1, b2a, c0, 0, 0, 0);
        c1 = __builtin_amdgcn_mfma_f32_32x32x16_bf16(A1, b2b, c1, 0, 0, 0);
        c0 = __builtin_amdgcn_mfma_f32_32x32x16_bf16(A2, b1a, c0, 0, 0, 0);
        c1 = __builtin_amdgcn_mfma_f32_32x32x16_bf16(A2, b1b, c1, 0, 0, 0);
        c0 = __builtin_amdgcn_mfma_f32_32x32x16_bf16(A1, b3a, c0, 0, 0, 0);
        c1 = __builtin_amdgcn_mfma_f32_32x32x16_bf16(A1, b3b, c1, 0, 0, 0);
        c0 = __builtin_amdgcn_mfma_f32_32x32x16_bf16(A3, b1a, c0, 0, 0, 0);
        c1 = __builtin_amdgcn_mfma_f32_32x32x16_bf16(A3, b1b, c1, 0, 0, 0);
        c0 = __builtin_amdgcn_mfma_f32_32x32x16_bf16(A2, b2a, c0, 0, 0, 0);
        c1 = __builtin_amdgcn_mfma_f32_32x32x16_bf16(A2, b2b, c1, 0, 0, 0);

        cur0 = nxt0; cur1 = nxt1; nxt0 = f0; nxt1 = f1;
        ap += 16; b1p += 512; b2p += 512; b3p += 512;
    }

    // per-token partial sumsq (lanes l and l+32 share a token)
    sq += __shfl_xor(sq, 32);
    if (lane < 32) sqred[w][l31] = sq;

    // stage 1: waves 4..7 deposit
    if (w >= 4) {
#pragma unroll
        for (int r = 0; r < 16; ++r) {
            red[w - 4][lane][r]      = c0[r];
            red[w - 4][lane][16 + r] = c1[r];
        }
    }
    __syncthreads();

    // L2-norm scale per token (full K)
    if (t < 32) {
        float q = 0.f;
#pragma unroll
        for (int ww = 0; ww < 8; ++ww) q += sqred[ww][t];
        scl[t] = SCALE / fmaxf(sqrtf(q), EPS);
    }

    // stage 2: waves 0..3 fold their registers in (thread-private cells)
    if (w < 4) {
#pragma unroll
        for (int r = 0; r < 16; ++r) {
            red[w][lane][r]      = c0[r] + red[w][lane][r];
            red[w][lane][16 + r] = c1[r] + red[w][lane][16 + r];
        }
    }
    __syncthreads();

    // gather: wave w owns regs R = 4w..4w+3 (= 16*tile + 4*wm + j);
    // token=(R&3)+8*((R&15)>>2)+4*half, expert = l31 + 32*tile
    const int wm = w & 3, tile = w >> 2;
    const int et = l31 + 32 * tile;
#pragma unroll
    for (int j = 0; j < 4; ++j) {
        const int R = 4 * w + j;
        const float a = red[0][lane][R] + red[1][lane][R] +
                        red[2][lane][R] + red[3][lane][R];
        const int token = j + 8 * wm + 4 * half;
        res[token][et] = a * scl[token];
    }
    __syncthreads();

    // coalesced outR write: thread t -> token t>>4, float4 quad t&15
    {
        const int token = t >> 4, q4 = (t & 15) * 4;
        *(float4*)(outR + (size_t)(tb + token) * NE + q4) =
            *(const float4*)(&res[token][q4]);
    }

    // fused top-8: wave w handles tokens 4w..4w+3.
    // 64-bit key = sortable(f32)<<32 | (63-e): max-reduce = highest value,
    // ties -> lowest expert index (= jax.lax.top_k order).
#pragma unroll 1
    for (int tt = 0; tt < 4; ++tt) {
        const int token = 4 * w + tt;
        const float v = res[token][lane];
        const unsigned u = __builtin_bit_cast(unsigned, v);
        const unsigned s = u ^ ((unsigned)(((int)u) >> 31) | 0x80000000u);
        unsigned long long cur = ((unsigned long long)s << 32) | (unsigned)(63 - lane);

        float bw = 0.f;
        int   bi = 0;
#pragma unroll
        for (int m = 0; m < TOPK; ++m) {
            unsigned long long r = cur;
#pragma unroll
            for (int d = 32; d >= 1; d >>= 1) {
                const unsigned long long o = __shfl_xor(r, d);
                r = (o > r) ? o : r;
            }
            const int we = 63 - (int)(r & 63ull);   // uniform across wave
            const float bv = __shfl(v, we);
            if (lane == we) cur = 0ull;             // remove winner
            if (lane == m) { bw = bv; bi = we; }
        }
        if (lane < TOPK) {
            const size_t ob = (size_t)(tb + token) * TOPK + lane;
            outW[ob] = log1pf(expf(bw));
            outI[ob] = (float)bi;
        }
    }
}

extern "C" void kernel_launch(void* const* d_in, const int* in_sizes, int n_in,
                              void* d_out, int out_size, void* d_ws, size_t ws_size,
                              hipStream_t stream) {
    const float* x   = (const float*)d_in[0];
    const float* sig = (const float*)d_in[1];
    float* out  = (float*)d_out;
    float* outW = out;
    float* outI = out + (size_t)N_TOKENS * TOPK;
    float* outR = out + (size_t)N_TOKENS * TOPK * 2;

    const size_t SIGE = (size_t)NE * DIM;   // 262144 elems per plane
    short* sh1 = (short*)d_ws;              // 3 planes = 1.5 MB total
    short* sh2 = sh1 + SIGE;
    short* sh3 = sh2 + SIGE;

    convert_sig<<<128, 256, 0, stream>>>(sig, sh1, sh2, sh3);
    gemm_fused<<<N_TOKENS / 32, 512, 0, stream>>>(x, sh1, sh2, sh3, outR, outW, outI);
}

// Round 4
// 386.391 us; speedup vs baseline: 1.3217x; 1.0264x over previous
//
#include <hip/hip_runtime.h>
#include <cmath>

// DarwinianRouter r8.
// Budget model: 396.6 = fill 161 (harness poison) + convert ~10 + gemm ~155
// (below top-5 cutoff) + ~70 gaps. gemm is ~3.8x over its 41us HBM floor with
// all pipes idle => memory-latency-bound on the A scatter (each A float4 instr
// = 32 rows x 16KB stride = 32 scattered transactions, 2KB/wave in flight).
// r8: block-cooperative A staging. All 8 waves share a K=128 slab of all 32
// rows (16KB LDS, double-buffered); wave w consumes k-subrange w*16. Stage =
// 2 global_load_lds dwordx4 per wave, LINEAR LDS dest (HW rule) + XOR-swizzled
// GLOBAL source (j' = j ^ (r&7)); ds_read applies the same swizzle (rule #21).
// Each stage instr = 8 fully-consumed 128B lines. 2-phase loop
// [stage s+1][compute s][barrier]; slab LDS unions with epilogue LDS (45KB).
// Epilogue/top-8/numerics unchanged from r7.

#define N_TOKENS 16384
#define DIM      4096
#define NE       64
#define TOPK     8
#define SCALE    5.0f
#define EPS      1e-12f
#define NSLAB    32        // K slabs of 128

typedef short  frag   __attribute__((ext_vector_type(8)));   // 8 bf16 bit-patterns
typedef float  f32x16 __attribute__((ext_vector_type(16)));  // 32x32 C/D
typedef int    i32x4  __attribute__((ext_vector_type(4)));

__device__ __forceinline__ void split3(float v, unsigned& h1, unsigned& h2, unsigned& h3) {
    unsigned u  = __builtin_bit_cast(unsigned, v);
    unsigned r1 = (u + 0x7FFFu + ((u >> 16) & 1u)) & 0xFFFF0000u;
    float    d1 = v - __builtin_bit_cast(float, r1);
    unsigned w  = __builtin_bit_cast(unsigned, d1);
    unsigned r2 = (w + 0x7FFFu + ((w >> 16) & 1u)) & 0xFFFF0000u;
    float    d2 = d1 - __builtin_bit_cast(float, r2);
    unsigned z  = __builtin_bit_cast(unsigned, d2);
    unsigned r3 = (z + 0x7FFFu + ((z >> 16) & 1u)) & 0xFFFF0000u;
    h1 = r1 >> 16; h2 = r2 >> 16; h3 = r3 >> 16;
}

// sig split + repack, frag-coalesced layout: plane[tile(2)][kb(256)][lane(64)][8],
// lane = (hf<<5)|e31; element (lane,i) = split(sig[e=tile*32+e31][k=kb*16+hf*8+i]).
__launch_bounds__(256)
__global__ void convert_sig(const float* __restrict__ sig,
                            short* __restrict__ h1,
                            short* __restrict__ h2,
                            short* __restrict__ h3) {
    const int tid  = blockIdx.x * 256 + threadIdx.x;   // 32768 threads (128 blocks)
    const int lane = tid & 63;
    const int kb   = (tid >> 6) & 255;
    const int tile = tid >> 14;
    const int e31  = lane & 31, hf = lane >> 5;
    const float* src = sig + (size_t)(tile * 32 + e31) * DIM + kb * 16 + hf * 8;
    const float4 v0 = *(const float4*)(src);
    const float4 v1 = *(const float4*)(src + 4);
    const float vs[8] = {v0.x, v0.y, v0.z, v0.w, v1.x, v1.y, v1.z, v1.w};
    frag o1, o2, o3;
#pragma unroll
    for (int p = 0; p < 8; ++p) {
        unsigned a, b, c;
        split3(vs[p], a, b, c);
        o1[p] = (short)a; o2[p] = (short)b; o3[p] = (short)c;
    }
    const int base = ((tile * 256 + kb) * 64 + lane) * 8;
    *(frag*)(h1 + base) = o1;
    *(frag*)(h2 + base) = o2;
    *(frag*)(h3 + base) = o3;
}

// stage one 16KB slab (32 rows x 128 floats) into LDS, linear dest, swizzled src.
// slot i = w*64 + lane (+512): row r = i>>5, global 16B-slot j = (i&31) ^ (r&7).
__device__ __forceinline__ void stage_slab(const float* __restrict__ x, int tb,
                                           int c0, float* slabbuf, int w, int lane) {
    const int i1 = w * 64 + lane;
    const int r1 = i1 >> 5;
    const int j1 = (i1 & 31) ^ (r1 & 7);
    const float* g1 = x + (size_t)(tb + r1) * DIM + c0 + 4 * j1;
    const int i2 = i1 + 512;
    const int r2 = i2 >> 5;
    const int j2 = (i2 & 31) ^ (r2 & 7);
    const float* g2 = x + (size_t)(tb + r2) * DIM + c0 + 4 * j2;
    float* l1 = slabbuf + w * 256;          // byte base w*1024 (wave-uniform)
    float* l2 = slabbuf + w * 256 + 2048;   // byte base w*1024 + 8192
    __builtin_amdgcn_global_load_lds(
        (const __attribute__((address_space(1))) void*)g1,
        (__attribute__((address_space(3))) void*)l1, 16, 0, 0);
    __builtin_amdgcn_global_load_lds(
        (const __attribute__((address_space(1))) void*)g2,
        (__attribute__((address_space(3))) void*)l2, 16, 0, 0);
}

// grid N_TOKENS/32 blocks x 512 threads (8 waves). Block owns 32 tokens,
// full K=4096 in 32 shared slabs of 128; wave w handles k = s*128 + w*16 + [0,16).
__launch_bounds__(512, 4)
__global__ void gemm_fused(const float* __restrict__ x,
                           const short* __restrict__ sh1,
                           const short* __restrict__ sh2,
                           const short* __restrict__ sh3,
                           float* __restrict__ outR,
                           float* __restrict__ outW,
                           float* __restrict__ outI) {
    // union: slab[2][4096] f32 (32KB, main loop) / epilogue structs (44.7KB)
    __shared__ __align__(16) char smem[45056];
    float* slab = (float*)smem;
    float (*red)[64][34] = (float(*)[64][34])smem;            // [4][64][34]
    float (*res)[68]     = (float(*)[68])(smem + 34816);      // [32][68]
    float (*sqred)[32]   = (float(*)[32])(smem + 43520);      // [8][32]
    float* scl           = (float*)(smem + 44544);            // [32]

    const int t    = threadIdx.x;
    const int lane = t & 63;
    const int w    = t >> 6;
    const int l31  = lane & 31;
    const int half = lane >> 5;

    const int tb = blockIdx.x * 32;

    // B: packed layout; wave w at slab s uses kb = s*8 + w -> advance 4096/slab
    const short* b1p = sh1 + ((size_t)(w * 64) + lane) * 8;
    const short* b2p = sh2 + ((size_t)(w * 64) + lane) * 8;
    const short* b3p = sh3 + ((size_t)(w * 64) + lane) * 8;
    const int TILE1 = 256 * 64 * 8;               // +tile1 (experts 32..63)

    f32x16 c0 = {};   // experts 0..31
    f32x16 c1 = {};   // experts 32..63
    float sq = 0.f;

    // swizzled LDS read address pieces for this lane's A-frag
    const int kk = 4 * w + 2 * half;              // 16B-slot index within row
    const int rr = l31;
    const int roff = rr * 128;
    const int sl0 = (kk ^ (rr & 7)) * 4;
    const int sl1 = ((kk + 1) ^ (rr & 7)) * 4;

    stage_slab(x, tb, 0, slab, w, lane);
    __syncthreads();   // drains vmcnt -> slab 0 resident for all waves

#pragma unroll 1
    for (int s = 0; s < NSLAB; ++s) {
        const int b = s & 1;
        if (s + 1 < NSLAB)
            stage_slab(x, tb, (s + 1) * 128, slab + (1 - b) * 4096, w, lane);

        const frag b1a = *(const frag*)(b1p);
        const frag b1b = *(const frag*)(b1p + TILE1);
        const frag b2a = *(const frag*)(b2p);
        const frag b2b = *(const frag*)(b2p + TILE1);
        const frag b3a = *(const frag*)(b3p);
        const frag b3b = *(const frag*)(b3p + TILE1);

        const float* base = slab + b * 4096 + roff;
        const float4 va = *(const float4*)(base + sl0);
        const float4 vb = *(const float4*)(base + sl1);

        const float vals[8] = {va.x, va.y, va.z, va.w, vb.x, vb.y, vb.z, vb.w};
        i32x4 a1i, a2i, a3i;
#pragma unroll
        for (int p = 0; p < 4; ++p) {
            const float v0 = vals[2 * p], v1 = vals[2 * p + 1];
            sq = fmaf(v0, v0, sq);
            sq = fmaf(v1, v1, sq);
            unsigned h10, h20, h30, h11, h21, h31;
            split3(v0, h10, h20, h30);
            split3(v1, h11, h21, h31);
            a1i[p] = (int)(h10 | (h11 << 16));
            a2i[p] = (int)(h20 | (h21 << 16));
            a3i[p] = (int)(h30 | (h31 << 16));
        }
        const frag A1 = __builtin_bit_cast(frag, a1i);
        const frag A2 = __builtin_bit_cast(frag, a2i);
        const frag A3 = __builtin_bit_cast(frag, a3i);

        // 6 products/tile: h1h1 + (h1h2+h2h1) + (h1h3+h3h1+h2h2)
        c0 = __builtin_amdgcn_mfma_f32_32x32x16_bf16(A1, b1a, c0, 0, 0, 0);
        c1 = __builtin_amdgcn_mfma_f32_32x32x16_bf16(A1, b1b, c1, 0, 0, 0);
        c0 = __builtin_amdgcn_mfma_f32_32x32x16_bf16(A1, b2a, c0, 0, 0, 0);
        c1 = __builtin_amdgcn_mfma_f32_32x32x16_bf16(A1, b2b, c1, 0, 0, 0);
        c0 = __builtin_amdgcn_mfma_f32_32x32x16_bf16(A2, b1a, c0, 0, 0, 0);
        c1 = __builtin_amdgcn_mfma_f32_32x32x16_bf16(A2, b1b, c1, 0, 0, 0);
        c0 = __builtin_amdgcn_mfma_f32_32x32x16_bf16(A1, b3a, c0, 0, 0, 0);
        c1 = __builtin_amdgcn_mfma_f32_32x32x16_bf16(A1, b3b, c1, 0, 0, 0);
        c0 = __builtin_amdgcn_mfma_f32_32x32x16_bf16(A3, b1a, c0, 0, 0, 0);
        c1 = __builtin_amdgcn_mfma_f32_32x32x16_bf16(A3, b1b, c1, 0, 0, 0);
        c0 = __builtin_amdgcn_mfma_f32_32x32x16_bf16(A2, b2a, c0, 0, 0, 0);
        c1 = __builtin_amdgcn_mfma_f32_32x32x16_bf16(A2, b2b, c1, 0, 0, 0);

        b1p += 4096; b2p += 4096; b3p += 4096;
        __syncthreads();   // slab s+1 resident; slab s reads complete
    }

    // per-token partial sumsq (lanes l and l+32 share a token)
    sq += __shfl_xor(sq, 32);
    if (lane < 32) sqred[w][l31] = sq;

    // stage 1: waves 4..7 deposit (slab LDS dead; red/res alias it)
    if (w >= 4) {
#pragma unroll
        for (int r = 0; r < 16; ++r) {
            red[w - 4][lane][r]      = c0[r];
            red[w - 4][lane][16 + r] = c1[r];
        }
    }
    __syncthreads();

    // L2-norm scale per token (full K)
    if (t < 32) {
        float q = 0.f;
#pragma unroll
        for (int ww = 0; ww < 8; ++ww) q += sqred[ww][t];
        scl[t] = SCALE / fmaxf(sqrtf(q), EPS);
    }

    // stage 2: waves 0..3 fold their registers in (thread-private cells)
    if (w < 4) {
#pragma unroll
        for (int r = 0; r < 16; ++r) {
            red[w][lane][r]      = c0[r] + red[w][lane][r];
            red[w][lane][16 + r] = c1[r] + red[w][lane][16 + r];
        }
    }
    __syncthreads();

    // gather: wave w owns regs R = 4w..4w+3 (= 16*tile + 4*wm + j);
    // token=(R&3)+8*((R&15)>>2)+4*half, expert = l31 + 32*tile
    const int wm = w & 3, tile = w >> 2;
    const int et = l31 + 32 * tile;
#pragma unroll
    for (int j = 0; j < 4; ++j) {
        const int R = 4 * w + j;
        const float a = red[0][lane][R] + red[1][lane][R] +
                        red[2][lane][R] + red[3][lane][R];
        const int token = j + 8 * wm + 4 * half;
        res[token][et] = a * scl[token];
    }
    __syncthreads();

    // coalesced outR write: thread t -> token t>>4, float4 quad t&15
    {
        const int token = t >> 4, q4 = (t & 15) * 4;
        *(float4*)(outR + (size_t)(tb + token) * NE + q4) =
            *(const float4*)(&res[token][q4]);
    }

    // fused top-8: wave w handles tokens 4w..4w+3.
    // 64-bit key = sortable(f32)<<32 | (63-e): max-reduce = highest value,
    // ties -> lowest expert index (= jax.lax.top_k order).
#pragma unroll 1
    for (int tt = 0; tt < 4; ++tt) {
        const int token = 4 * w + tt;
        const float v = res[token][lane];
        const unsigned u = __builtin_bit_cast(unsigned, v);
        const unsigned sbits = u ^ ((unsigned)(((int)u) >> 31) | 0x80000000u);
        unsigned long long cur = ((unsigned long long)sbits << 32) | (unsigned)(63 - lane);

        float bw = 0.f;
        int   bi = 0;
#pragma unroll
        for (int m = 0; m < TOPK; ++m) {
            unsigned long long r = cur;
#pragma unroll
            for (int d = 32; d >= 1; d >>= 1) {
                const unsigned long long o = __shfl_xor(r, d);
                r = (o > r) ? o : r;
            }
            const int we = 63 - (int)(r & 63ull);   // uniform across wave
            const float bv = __shfl(v, we);
            if (lane == we) cur = 0ull;             // remove winner
            if (lane == m) { bw = bv; bi = we; }
        }
        if (lane < TOPK) {
            const size_t ob = (size_t)(tb + token) * TOPK + lane;
            outW[ob] = log1pf(expf(bw));
            outI[ob] = (float)bi;
        }
    }
}

extern "C" void kernel_launch(void* const* d_in, const int* in_sizes, int n_in,
                              void* d_out, int out_size, void* d_ws, size_t ws_size,
                              hipStream_t stream) {
    const float* x   = (const float*)d_in[0];
    const float* sig = (const float*)d_in[1];
    float* out  = (float*)d_out;
    float* outW = out;
    float* outI = out + (size_t)N_TOKENS * TOPK;
    float* outR = out + (size_t)N_TOKENS * TOPK * 2;

    const size_t SIGE = (size_t)NE * DIM;   // 262144 elems per plane
    short* sh1 = (short*)d_ws;              // 3 planes = 1.5 MB total
    short* sh2 = sh1 + SIGE;
    short* sh3 = sh2 + SIGE;

    convert_sig<<<128, 256, 0, stream>>>(sig, sh1, sh2, sh3);
    gemm_fused<<<N_TOKENS / 32, 512, 0, stream>>>(x, sh1, sh2, sh3, outR, outW, outI);
}